// Round 1
// baseline (47230.618 us; speedup 1.0000x reference)
//
#include <hip/hip_runtime.h>
#include <math.h>

#define BB 512      // batch
#define NN 5184     // high-res dim
#define MM 81       // low-res dim
#define MP 84       // padded M (84*4B = 336B, 16B-aligned rows)
#define KP (MP/4)   // 21 float4 per row
#define NITER 100
#define BLK 1024
#define BK 4        // batch items per workgroup
#define NWG (BB/BK) // 128 workgroups
#define NCHUNK 12
#define CHN (NN/NCHUNK) // 432

// ---- pad mat [5184][81] -> matp [5184][84] (zeros in cols 81..83) ----
__global__ void prep_pad(const float* __restrict__ mat, float* __restrict__ matp) {
    int i = blockIdx.x * blockDim.x + threadIdx.x;
    if (i >= NN * MP) return;
    int n = i / MP, m = i - n * MP;
    matp[i] = (m < MM) ? mat[n * MM + m] : 0.0f;
}

template <bool PADDED>
__device__ __forceinline__ float4 loadrow(const float* __restrict__ m, int n, int k4) {
    if constexpr (PADDED) {
        return reinterpret_cast<const float4*>(m + (size_t)n * MP)[k4];
    } else {
        const float* r = m + (size_t)n * MM + k4 * 4;
        float4 v;
        v.x = r[0];
        if (k4 < KP - 1) { v.y = r[1]; v.z = r[2]; v.w = r[3]; }
        else { v.y = 0.0f; v.z = 0.0f; v.w = 0.0f; }
        return v;
    }
}

// Phase A for R rows per thread: re = z@mat^T rows, then y update (soft-thresh + momentum)
template <int R, bool PADDED>
__device__ __forceinline__ void phaseA_rows(const int* ns, const float* __restrict__ matsrc,
                                            const float4 (*zl4)[KP], float* __restrict__ y,
                                            int b0, float thr, float coef, int it) {
    float re[R][BK];
#pragma unroll
    for (int i = 0; i < R; ++i)
#pragma unroll
        for (int b = 0; b < BK; ++b) re[i][b] = 0.0f;

#pragma unroll
    for (int k = 0; k < KP; ++k) {
        float4 rw[R];
#pragma unroll
        for (int i = 0; i < R; ++i) rw[i] = loadrow<PADDED>(matsrc, ns[i], k);
#pragma unroll
        for (int b = 0; b < BK; ++b) {
            float4 z = zl4[b][k];
#pragma unroll
            for (int i = 0; i < R; ++i)
                re[i][b] += rw[i].x * z.x + rw[i].y * z.y + rw[i].z * z.z + rw[i].w * z.w;
        }
    }
#pragma unroll
    for (int i = 0; i < R; ++i) {
#pragma unroll
        for (int b = 0; b < BK; ++b) {
            size_t idx = (size_t)(b0 + b) * NN + ns[i];
            float yo = (it == 0) ? 0.0f : y[idx];
            float w = yo + re[i][b];                                   // MU = 1
            float yn = fmaxf(w - thr, 0.0f) + fminf(w + thr, 0.0f);    // soft-threshold
            y[idx] = yn + coef * (yn - yo);                            // FISTA momentum
        }
    }
}

template <bool PADDED>
__global__ __launch_bounds__(BLK) void fista_kernel(const float* __restrict__ x,
                                                    const float* __restrict__ matsrc,
                                                    const float* __restrict__ lam,
                                                    float* __restrict__ y /* = d_out */) {
    __shared__ float4 zl4[BK][KP];               // z = xf - y@mat, padded
    __shared__ float4 xfl4[BK][KP];              // xf cached
    __shared__ float4 up4[NCHUNK][BK][KP];       // down-proj partials

    const int tid = threadIdx.x;
    const int b0 = blockIdx.x * BK;
    const float thr = lam[0];                    // lam / MU, MU = 1

    // stage xf into LDS (zero-padded), init z = xf (y0 = 0 -> u0 = 0)
    for (int i = tid; i < BK * MP; i += BLK) {
        int b = i / MP, m = i - b * MP;
        float v = (m < MM) ? x[(size_t)(b0 + b) * MM + m] : 0.0f;
        ((float*)xfl4)[i] = v;
        ((float*)zl4)[i] = v;
    }
    __syncthreads();

    float t = 1.0f;
    for (int it = 0; it < NITER; ++it) {
        float tn = (1.0f + sqrtf(1.0f + t * t)) * 0.5f;
        float coef = (t - 1.0f) / tn;
        t = tn;

        // ---- Phase A: per-thread rows n = tid + 1024*r (r=0..4), plus r=5 for tid<64 ----
        {
            int ns3[3] = {tid, tid + 1024, tid + 2048};
            phaseA_rows<3, PADDED>(ns3, matsrc, zl4, y, b0, thr, coef, it);
            int ns2[2] = {tid + 3072, tid + 4096};
            phaseA_rows<2, PADDED>(ns2, matsrc, zl4, y, b0, thr, coef, it);
            if (tid < 64) {
                int ns1[1] = {5120 + tid};
                phaseA_rows<1, PADDED>(ns1, matsrc, zl4, y, b0, thr, coef, it);
            }
        }
        if (it == NITER - 1) break;   // final y already in d_out
        __syncthreads();              // y visible to whole block

        // ---- Phase B: u[b][m] = sum_n y[b][n]*mat[n][m], chunked over n ----
        if (tid < NCHUNK * BK * KP) { // 1008 tasks
            int m4 = tid % KP;
            int cb = tid / KP;
            int b = cb & (BK - 1);
            int chunk = cb >> 2;
            int nbase = chunk * CHN;
            const float4* yrow = reinterpret_cast<const float4*>(y + (size_t)(b0 + b) * NN);
            float4 acc = {0.0f, 0.0f, 0.0f, 0.0f};
            for (int kk = 0; kk < CHN / 4; ++kk) {  // 108 steps of 4 rows
                int n = nbase + kk * 4;
                float4 y4 = yrow[(nbase >> 2) + kk];             // broadcast in 21-lane group
                float4 r0 = loadrow<PADDED>(matsrc, n + 0, m4);  // coalesced across m4 lanes
                float4 r1 = loadrow<PADDED>(matsrc, n + 1, m4);
                float4 r2 = loadrow<PADDED>(matsrc, n + 2, m4);
                float4 r3 = loadrow<PADDED>(matsrc, n + 3, m4);
                acc.x += y4.x * r0.x + y4.y * r1.x + y4.z * r2.x + y4.w * r3.x;
                acc.y += y4.x * r0.y + y4.y * r1.y + y4.z * r2.y + y4.w * r3.y;
                acc.z += y4.x * r0.z + y4.y * r1.z + y4.z * r2.z + y4.w * r3.z;
                acc.w += y4.x * r0.w + y4.y * r1.w + y4.z * r2.w + y4.w * r3.w;
            }
            up4[chunk][b][m4] = acc;
        }
        __syncthreads();

        // ---- reduce partials, z = xf - u ----
        if (tid < BK * KP) {  // 84 threads
            int b = tid / KP, m4 = tid - b * KP;
            float4 s = {0.0f, 0.0f, 0.0f, 0.0f};
#pragma unroll
            for (int c = 0; c < NCHUNK; ++c) {
                float4 p = up4[c][b][m4];
                s.x += p.x; s.y += p.y; s.z += p.z; s.w += p.w;
            }
            float4 xv = xfl4[b][m4];
            float4 zz = {xv.x - s.x, xv.y - s.y, xv.z - s.z, xv.w - s.w};
            zl4[b][m4] = zz;
        }
        __syncthreads();
    }
}

extern "C" void kernel_launch(void* const* d_in, const int* in_sizes, int n_in,
                              void* d_out, int out_size, void* d_ws, size_t ws_size,
                              hipStream_t stream) {
    const float* x   = (const float*)d_in[0];   // [512,9,9] fp32, row-major == [512][81]
    const float* mat = (const float*)d_in[1];   // [5184,81] fp32
    const float* lam = (const float*)d_in[2];   // [1] fp32
    float* out = (float*)d_out;                 // [512,5184] fp32, doubles as y state

    size_t matp_bytes = (size_t)NN * MP * sizeof(float);
    if (ws_size >= matp_bytes) {
        float* matp = (float*)d_ws;
        prep_pad<<<(NN * MP + 255) / 256, 256, 0, stream>>>(mat, matp);
        fista_kernel<true><<<NWG, BLK, 0, stream>>>(x, matp, lam, out);
    } else {
        fista_kernel<false><<<NWG, BLK, 0, stream>>>(x, mat, lam, out);
    }
}

// Round 2
// 7305.232 us; speedup vs baseline: 6.4653x; 6.4653x over previous
//
#include <hip/hip_runtime.h>
#include <math.h>

#define NN 5184
#define MM 81
#define BTOT 512
#define NITER 100
#define NSL 64          // n-slices
#define BSL 4           // b-slices
#define NR 81           // n rows per WG (NN/NSL)
#define BR 128          // batch per WG (BTOT/BSL)
#define MP 84           // padded M
#define KP 21           // MP/4 float4
#define THREADS 1024
#define GRID (NSL*BSL)  // 256 WGs, 1 per CU
#define PSTRIDE (BTOT*MM)  // 41472 floats: slice stride in partials
// LDS: matL [81][84] + yL [128][81] + zL/uL/redz [128][84]
#define SMEM_FLOATS (NR*MP + BR*NR + BR*MP)
#define SMEM_BYTES (SMEM_FLOATS*4)   // 111,696 B -> 1 WG/CU guaranteed

__global__ void init_sync(unsigned* cnt) { *cnt = 0u; }

__device__ __forceinline__ void grid_barrier(unsigned* cnt, unsigned target) {
    __syncthreads();
    if (threadIdx.x == 0) {
        __hip_atomic_fetch_add(cnt, 1u, __ATOMIC_ACQ_REL, __HIP_MEMORY_SCOPE_AGENT);
        while (__hip_atomic_load(cnt, __ATOMIC_ACQUIRE, __HIP_MEMORY_SCOPE_AGENT) < target)
            __builtin_amdgcn_s_sleep(8);
    }
    __syncthreads();
}

__global__ __launch_bounds__(THREADS, 4) void fista(
        const float* __restrict__ x, const float* __restrict__ mat,
        const float* __restrict__ lam, float* __restrict__ out,
        float* __restrict__ zbuf, unsigned* __restrict__ cnt) {
    extern __shared__ float smem[];
    float*  matLf = smem;                      // [NR][MP]
    float*  yL    = smem + NR*MP;              // [BR][NR]
    float*  zLf   = smem + NR*MP + BR*NR;      // [BR][MP]  (also uL, also redz)
    float4* matL4 = (float4*)matLf;
    float4* zL4   = (float4*)zLf;

    const int tid = threadIdx.x;
    const int bid = blockIdx.x;
    const int nsl = bid >> 2;                  // 0..63
    const int bsl = bid & 3;                   // 0..3
    const int n0  = nsl * NR;
    const int b0  = bsl * BR;
    float* partials = out;                     // [NSL][BTOT][MM] == out exactly

    // ---- one-time init: mat slice, y=0, z=xf ----
    for (int i = tid; i < NR*MP; i += THREADS) {
        int r = i / MP, m = i - r*MP;
        matLf[i] = (m < MM) ? mat[(size_t)(n0 + r)*MM + m] : 0.f;
    }
    for (int i = tid; i < BR*NR; i += THREADS) yL[i] = 0.f;
    for (int i = tid; i < BR*MP; i += THREADS) {
        int b = i / MP, m = i - b*MP;
        zLf[i] = (m < MM) ? x[(size_t)(b0 + b)*MM + m] : 0.f;
    }
    __syncthreads();

    const float thr  = lam[0];                 // lam/MU, MU=1
    const int wv = tid >> 6, lane = tid & 63;
    const int bb = wv << 3;                    // wave's 8-batch tile base
    const int m4 = lane % KP;                  // phase-B column (float4)
    const int ns3 = lane / KP;                 // phase-B n-subgroup 0..2 (3 -> idle)
    float t = 1.f;
    unsigned bar = 0;

    for (int it = 0; it < NITER; ++it) {
        float tn = (1.f + sqrtf(1.f + t*t)) * 0.5f;
        float coef = (t - 1.f) / tn;
        t = tn;

        // ---- Phase A: re = z @ mat^T (own tile), soft-thresh + momentum ----
        for (int p = 0; p < 2; ++p) {
            int n = (p << 6) + lane;
            if (n < NR) {
                float re[8];
#pragma unroll
                for (int b = 0; b < 8; ++b) re[b] = 0.f;
                for (int k = 0; k < KP; ++k) {
                    float4 mv = matL4[n*KP + k];
#pragma unroll
                    for (int b = 0; b < 8; ++b) {
                        float4 zv = zL4[(bb + b)*KP + k];   // wave-uniform -> broadcast
                        re[b] += zv.x*mv.x + zv.y*mv.y + zv.z*mv.z + zv.w*mv.w;
                    }
                }
#pragma unroll
                for (int b = 0; b < 8; ++b) {
                    float* yp = &yL[(bb + b)*NR + n];
                    float yo = *yp;
                    float w  = yo + re[b];
                    float yn = fmaxf(w - thr, 0.f) + fminf(w + thr, 0.f);
                    *yp = yn + coef*(yn - yo);
                }
            }
        }
        if (it == NITER - 1) break;
        __syncthreads();

        // ---- Phase B: uL[b][m] = sum_{n in slice} yL[b][n]*matL[n][m] ----
        {
            float4 acc[8];
#pragma unroll
            for (int b = 0; b < 8; ++b) acc[b] = float4{0.f,0.f,0.f,0.f};
            if (ns3 < 3) {
                const int nb = ns3 * 27;
                for (int s = 0; s < 27; ++s) {
                    int n = nb + s;
                    float4 mv = matL4[n*KP + m4];
#pragma unroll
                    for (int b = 0; b < 8; ++b) {
                        float yv = yL[(bb + b)*NR + n];     // 3 addrs per wave
                        acc[b].x += yv*mv.x; acc[b].y += yv*mv.y;
                        acc[b].z += yv*mv.z; acc[b].w += yv*mv.w;
                    }
                }
            }
            // 3-pass in-wave reduce into zL4 (now uL); in-order ds ops per wave
            for (int g = 0; g < 3; ++g) {
                if (ns3 == g) {
#pragma unroll
                    for (int b = 0; b < 8; ++b) {
                        int ui = (bb + b)*KP + m4;
                        if (g == 0) zL4[ui] = acc[b];
                        else {
                            float4 u = zL4[ui];
                            u.x += acc[b].x; u.y += acc[b].y;
                            u.z += acc[b].z; u.w += acc[b].w;
                            zL4[ui] = u;
                        }
                    }
                }
            }
        }
        __syncthreads();

        // ---- write partial u tile to global (coalesced) ----
        {
            size_t pbase = ((size_t)nsl*BTOT + b0) * MM;
            for (int f = tid; f < BR*MM; f += THREADS) {
                int b = f / MM, m = f - b*MM;
                partials[pbase + f] = zLf[b*MP + m];
            }
        }
        grid_barrier(cnt, ++bar * (unsigned)GRID);

        // ---- Phase R: reduce 64 slices -> z for 2 owned batch rows ----
        {
            float* redzf = zLf;   // reuse (uL dead now)
            if (tid < 648) {
                int e = tid >> 2, q = tid & 3;          // e: 0..161, q: 0..3
                int blo = (e >= 81) ? 1 : 0;
                int m = e - (blo ? 81 : 0);
                int bg = b0 + 2*nsl + blo;
                const float* pp = partials + (size_t)bg*MM + m;
                float s = 0.f;
                int s0 = q << 4;
#pragma unroll 4
                for (int s2 = 0; s2 < 16; ++s2)
                    s += pp[(size_t)(s0 + s2) * PSTRIDE];
                redzf[tid] = s;
            }
            __syncthreads();
            if (tid < 162) {
                int blo = (tid >= 81) ? 1 : 0;
                int m = tid - (blo ? 81 : 0);
                int bg = b0 + 2*nsl + blo;
                float tot = redzf[tid*4] + redzf[tid*4+1] + redzf[tid*4+2] + redzf[tid*4+3];
                zbuf[(size_t)bg*MM + m] = x[(size_t)bg*MM + m] - tot;
            }
        }
        grid_barrier(cnt, ++bar * (unsigned)GRID);

        // ---- reload z tile (pads: mat pad cols are 0, so stale pads are harmless) ----
        {
            size_t zbase = (size_t)b0 * MM;
            for (int f = tid; f < BR*MM; f += THREADS) {
                int b = f / MM, m = f - b*MM;
                zLf[b*MP + m] = zbuf[zbase + f];
            }
        }
        __syncthreads();
    }

    // ---- final y -> out (overwrites partials; all partial reads done) ----
    __syncthreads();
    for (int i = tid; i < BR*NR; i += THREADS) {
        int b = i / NR, n = i - b*NR;
        out[(size_t)(b0 + b)*NN + n0 + n] = yL[i];
    }
}

extern "C" void kernel_launch(void* const* d_in, const int* in_sizes, int n_in,
                              void* d_out, int out_size, void* d_ws, size_t ws_size,
                              hipStream_t stream) {
    const float* x   = (const float*)d_in[0];   // [512,9,9] == [512][81]
    const float* mat = (const float*)d_in[1];   // [5184][81]
    const float* lam = (const float*)d_in[2];   // [1]
    float* out = (float*)d_out;                 // [512][5184]

    unsigned* cnt = (unsigned*)d_ws;
    float* zbuf = (float*)((char*)d_ws + 1024); // [512][81] = 166 KB

    hipFuncSetAttribute((const void*)fista,
                        hipFuncAttributeMaxDynamicSharedMemorySize, SMEM_BYTES);
    init_sync<<<1, 1, 0, stream>>>(cnt);
    fista<<<GRID, THREADS, SMEM_BYTES, stream>>>(x, mat, lam, out, zbuf, cnt);
}